// Round 11
// baseline (41.440 us; speedup 1.0000x reference)
//
#include <hip/hip_runtime.h>

#define NC 20
#define NCELL 49
#define NGT 32
#define NIMG 8192
#define IPB 4                       // images per block = 1 per wave
#define NBLK (NIMG / IPB)           // 2048 blocks
#define LAMBDA_COORD 5.0f
#define LAMBDA_NOOBJ 0.5f
#define EPS_IOU 1e-6f

// Wave = 1 image. img is wave-uniform => gt_boxes/gt_labels reads are scalar
// (s_load into SGPRs); the 32-GT loop is pure VALU with SGPR operands, no
// per-lane loads, no block barriers. Lane = 1 cell (both boxes), lanes 49-63
// clamped & zeroed. Argmax: 4 chains (2 boxes x low/high GT halves), S-form
// compare (in_j*bS > bin*S_j == IoU order), merge prefers low half on ties
// => exact first-index (jnp) semantics.
__global__ __launch_bounds__(256) void yolo_main_kernel(
    const float* __restrict__ outputs,     // [N, 49, 30]
    const float* __restrict__ gt_boxes,    // [N, 32, 4]
    const int*   __restrict__ gt_labels,   // [N, 32]
    float* __restrict__ partials)          // [NBLK]
{
    __shared__ float s_act[IPB][1472];     // 23552 B, per-wave private regions
    __shared__ float s_w[IPB];

    const int tid = threadIdx.x;
    const int wv  = tid >> 6;
    const int l   = tid & 63;
    const unsigned img =
        (unsigned)__builtin_amdgcn_readfirstlane((int)(blockIdx.x * IPB + wv));

    // ---- per-wave stage: 1470 floats as 735 float2, lanes stride 64 ----
    {
        const float2* src = reinterpret_cast<const float2*>(outputs + (size_t)img * 1470);
        float2* dst = reinterpret_cast<float2*>(&s_act[wv][0]);
        #pragma unroll
        for (int k = 0; k < 12; ++k) {
            int i = l + (k << 6);
            if (i < 735) dst[i] = src[i];
        }
    }
    // wave-private LDS: compiler inserts lgkmcnt waits; no __syncthreads needed

    // ---- uniform label mask (scalar loads + SALU) ----
    const int* lp = gt_labels + (size_t)img * NGT;
    unsigned mask = 0u;
    #pragma unroll
    for (int j = 0; j < NGT; ++j) mask |= (1u << lp[j]);
    mask = (unsigned)__builtin_amdgcn_readfirstlane((int)mask);
    const float kcnt = (float)__popc(mask);

    // ---- my cell (lanes >= 49 clamped; their partial is zeroed) ----
    const int lc = (l < NCELL) ? l : (NCELL - 1);
    const float* af = &s_act[wv][lc * 30];

    // CE pass 1: max + masked sum (streaming, low VGPR)
    const float2* a2c = reinterpret_cast<const float2*>(af + 10);
    float mx = -3.402823466e38f, sel = 0.f;
    #pragma unroll
    for (int k = 0; k < 10; ++k) {
        float2 v = a2c[k];
        mx = fmaxf(mx, fmaxf(v.x, v.y));
        sel += (((mask >> (2 * k)) & 1u) ? v.x : 0.f);
        sel += (((mask >> (2 * k + 1)) & 1u) ? v.y : 0.f);
    }
    // CE pass 2: exp-sum (re-read LDS)
    float ss = 0.f;
    #pragma unroll
    for (int k = 0; k < 10; ++k) {
        float2 v = a2c[k];
        ss += __expf(v.x - mx) + __expf(v.y - mx);
    }
    const float ce = kcnt * (mx + __logf(ss)) - sel;

    // ---- both boxes' registers ----
    const float2* ab = reinterpret_cast<const float2*>(af);
    float2 q0 = ab[0], q1 = ab[1], q2 = ab[2], q3 = ab[3], q4 = ab[4];
    const float cx0 = q0.x, cy0 = q0.y, w0 = q1.x, h0 = q1.y, cf0 = q2.x;
    const float cx1 = q2.y, cy1 = q3.x, w1 = q3.y, h1 = q4.x, cf1 = q4.y;
    const float px1_0 = fmaf(w0, -0.5f, cx0), py1_0 = fmaf(h0, -0.5f, cy0);
    const float px2_0 = fmaf(w0,  0.5f, cx0), py2_0 = fmaf(h0,  0.5f, cy0);
    const float px1_1 = fmaf(w1, -0.5f, cx1), py1_1 = fmaf(h1, -0.5f, cy1);
    const float px2_1 = fmaf(w1,  0.5f, cx1), py2_1 = fmaf(h1,  0.5f, cy1);
    const float pa0e = w0 * h0 + EPS_IOU, pa1e = w1 * h1 + EPS_IOU;

    // ---- GT loop: scalar (SGPR) GT operands, 4 independent chains ----
    const float4* gp = reinterpret_cast<const float4*>(gt_boxes) + (size_t)img * NGT;
    float binA0 = -1.f, bSA0 = 1.f, binB0 = -1.f, bSB0 = 1.f;
    float binA1 = -1.f, bSA1 = 1.f, binB1 = -1.f, bSB1 = 1.f;
    int biA0 = 0, biB0 = 16, biA1 = 0, biB1 = 16;

    #define UPDC(g, ga_, j_, bin_, bS_, bi_, px1_, py1_, px2_, py2_, pae_) do {  \
        float iw = fmaxf(fminf(px2_, (g).z) - fmaxf(px1_, (g).x), 0.f);          \
        float ih = fmaxf(fminf(py2_, (g).w) - fmaxf(py1_, (g).y), 0.f);          \
        float in_ = iw * ih, S_ = pae_ + (ga_);                                  \
        bool c_ = in_ * bS_ > bin_ * S_;                                         \
        bin_ = c_ ? in_ : bin_; bS_ = c_ ? S_ : bS_; bi_ = c_ ? (j_) : bi_;      \
    } while (0)

    #pragma unroll
    for (int j = 0; j < 16; ++j) {
        {   // low half: GT j  (uniform scalar data)
            float4 g = gp[j];
            float4 gc = make_float4(fmaf(g.z, -0.5f, g.x), fmaf(g.w, -0.5f, g.y),
                                    fmaf(g.z,  0.5f, g.x), fmaf(g.w,  0.5f, g.y));
            float ga = g.z * g.w;
            UPDC(gc, ga, j, binA0, bSA0, biA0, px1_0, py1_0, px2_0, py2_0, pa0e);
            UPDC(gc, ga, j, binA1, bSA1, biA1, px1_1, py1_1, px2_1, py2_1, pa1e);
        }
        {   // high half: GT j+16
            float4 g = gp[j + 16];
            float4 gc = make_float4(fmaf(g.z, -0.5f, g.x), fmaf(g.w, -0.5f, g.y),
                                    fmaf(g.z,  0.5f, g.x), fmaf(g.w,  0.5f, g.y));
            float ga = g.z * g.w;
            UPDC(gc, ga, j + 16, binB0, bSB0, biB0, px1_0, py1_0, px2_0, py2_0, pa0e);
            UPDC(gc, ga, j + 16, binB1, bSB1, biB1, px1_1, py1_1, px2_1, py2_1, pa1e);
        }
    }

    // merge low/high (take high iff strictly greater => first-index exact)
    const bool t0 = binB0 * bSA0 > binA0 * bSB0;
    const float bin0 = t0 ? binB0 : binA0;
    const float bS0  = t0 ? bSB0  : bSA0;
    const int   bi0  = t0 ? biB0  : biA0;
    const bool t1 = binB1 * bSA1 > binA1 * bSB1;
    const float bin1 = t1 ? binB1 : binA1;
    const float bS1  = t1 ? bSB1  : bSA1;
    const int   bi1  = t1 ? biB1  : biA1;

    // ---- epilogue: divergent gathered GT reads (L1-resident) ----
    float term0, term1;
    if (bin0 > 0.f) {
        float4 g = gp[bi0];
        const float iou = __fdividef(bin0, bS0 - bin0);
        const float dx = cx0 - g.x, dy = cy0 - g.y;
        const float dw = sqrtf(w0) - sqrtf(g.z);
        const float dh = sqrtf(h0) - sqrtf(g.w);
        term0 = LAMBDA_COORD * (dx * dx + dy * dy + dw * dw + dh * dh)
              + (cf0 - iou) * (cf0 - iou) + ce;
    } else {
        term0 = LAMBDA_NOOBJ * cf0 * cf0;
    }
    if (bin1 > 0.f) {
        float4 g = gp[bi1];
        const float iou = __fdividef(bin1, bS1 - bin1);
        const float dx = cx1 - g.x, dy = cy1 - g.y;
        const float dw = sqrtf(w1) - sqrtf(g.z);
        const float dh = sqrtf(h1) - sqrtf(g.w);
        term1 = LAMBDA_COORD * (dx * dx + dy * dy + dw * dw + dh * dh)
              + (cf1 - iou) * (cf1 - iou) + ce;
    } else {
        term1 = LAMBDA_NOOBJ * cf1 * cf1;
    }

    float partial = (l < NCELL) ? (term0 + term1) : 0.f;

    // ---- wave reduce -> s_w[wv]; one barrier; block sum -> partials ----
    #pragma unroll
    for (int o = 32; o > 0; o >>= 1)
        partial += __shfl_down(partial, o);
    if (l == 0) s_w[wv] = partial;
    __syncthreads();
    if (tid == 0)
        partials[blockIdx.x] = s_w[0] + s_w[1] + s_w[2] + s_w[3];
}

__global__ __launch_bounds__(256) void yolo_reduce_kernel(
    const float* __restrict__ partials, float* __restrict__ out)
{
    float s = 0.f;
    for (int i = threadIdx.x; i < NBLK; i += 256) s += partials[i];
    #pragma unroll
    for (int o = 32; o > 0; o >>= 1)
        s += __shfl_down(s, o);
    __shared__ float s_w[4];
    const int tid = threadIdx.x;
    if ((tid & 63) == 0) s_w[tid >> 6] = s;
    __syncthreads();
    if (tid == 0)
        out[0] = (s_w[0] + s_w[1] + s_w[2] + s_w[3]) * (1.0f / (float)NIMG);
}

extern "C" void kernel_launch(void* const* d_in, const int* in_sizes, int n_in,
                              void* d_out, int out_size, void* d_ws, size_t ws_size,
                              hipStream_t stream) {
    const float* outputs   = (const float*)d_in[0];
    const float* gt_boxes  = (const float*)d_in[1];
    const int*   gt_labels = (const int*)d_in[2];
    float* out      = (float*)d_out;
    float* partials = (float*)d_ws;          // NBLK floats = 8 KB

    yolo_main_kernel<<<NBLK, 256, 0, stream>>>(outputs, gt_boxes, gt_labels, partials);
    yolo_reduce_kernel<<<1, 256, 0, stream>>>(partials, out);
}

// Round 12
// 28.924 us; speedup vs baseline: 1.4327x; 1.4327x over previous
//
#include <hip/hip_runtime.h>

#define NC 20
#define NCELL 49
#define NGT 32
#define NIMG 8192
#define NTOT (NIMG * NCELL)        // 401408
#define CPB 128                    // cells per tile
#define NTILE (NTOT / CPB)         // 3136 tiles
#define PBLK 1024                  // persistent blocks = exactly 4 per CU
#define NSPAN 4                    // images spanned by 128 consecutive cells
#define LAMBDA_COORD 5.0f
#define LAMBDA_NOOBJ 0.5f
#define EPS_IOU 1e-6f

// Persistent-block, double-buffered version of the proven R6 kernel.
// Per tile: STAGE_ISSUE (global->regs, before compute) ... compute(cur) ...
// barrier ... STAGE_WRITE (regs->LDS buf^1) ... barrier.  T14 split: HBM
// latency hides under the current tile's compute.  Compute body = R6 verbatim.
__global__ __launch_bounds__(256, 4) void yolo_main_kernel(
    const float* __restrict__ outputs,     // [N, 49, 30]
    const float* __restrict__ gt_boxes,    // [N, 32, 4]
    const int*   __restrict__ gt_labels,   // [N, 32]
    float* __restrict__ partials)          // [PBLK]
{
    __shared__ float4   s_act4[2][CPB * 30 / 4];   // 2 x 15360 B
    __shared__ float4   s_gtc[2][NSPAN * NGT];     // 2 x 2048 B
    __shared__ float    s_ga [2][NSPAN * NGT];     // 2 x  512 B
    __shared__ unsigned s_mask[2][NSPAN];
    __shared__ float    s_w[4];

    const int tid = threadIdx.x;
    const int bid = blockIdx.x;
    const int nt  = 3 + (bid < (NTILE - 3 * PBLK) ? 1 : 0);   // 64 blocks get 4

    float acc = 0.f;

    // prefetch registers (live across compute)
    float4 r0, r1, r2, r3, gtr;
    int labr = 0;
    unsigned g_img = NIMG;   // staging thread's image (predication)

#define STAGE_ISSUE(base_, nb_) do {                                          \
    const float4* asrc_ = reinterpret_cast<const float4*>(outputs)            \
                        + (size_t)(base_) * 30 / 4;                           \
    r0 = asrc_[tid];                                                          \
    r1 = asrc_[tid + 256];                                                    \
    r2 = asrc_[tid + 512];                                                    \
    if (tid < 192) r3 = asrc_[tid + 768];                                     \
    const unsigned il_ = (base_) / NCELL;                                     \
    if (tid < 128) {                                                          \
        const unsigned g_ = (unsigned)tid >> 5;                               \
        g_img = il_ + g_;                                                     \
        if (g_img < NIMG)                                                     \
            gtr = reinterpret_cast<const float4*>(gt_boxes)[g_img * NGT + (tid & 31)]; \
    } else {                                                                  \
        const int t_ = tid - 128;                                             \
        const unsigned g_ = (unsigned)t_ >> 5;                                \
        g_img = il_ + g_;                                                     \
        if (g_img < NIMG) labr = gt_labels[g_img * NGT + (t_ & 31)];          \
        if (t_ < NSPAN) s_mask[nb_][t_] = 0u;                                 \
    }                                                                         \
} while (0)

#define STAGE_WRITE(nb_) do {                                                 \
    s_act4[nb_][tid]       = r0;                                              \
    s_act4[nb_][tid + 256] = r1;                                              \
    s_act4[nb_][tid + 512] = r2;                                              \
    if (tid < 192) s_act4[nb_][tid + 768] = r3;                               \
    if (tid < 128) {                                                          \
        if (g_img < NIMG) {                                                   \
            s_gtc[nb_][tid] = make_float4(fmaf(gtr.z, -0.5f, gtr.x),          \
                                          fmaf(gtr.w, -0.5f, gtr.y),          \
                                          fmaf(gtr.z,  0.5f, gtr.x),          \
                                          fmaf(gtr.w,  0.5f, gtr.y));         \
            s_ga[nb_][tid] = gtr.z * gtr.w;                                   \
        }                                                                     \
    } else {                                                                  \
        const int t_ = tid - 128;                                             \
        if (g_img < NIMG) atomicOr(&s_mask[nb_][t_ >> 5], 1u << labr);        \
    }                                                                         \
} while (0)

    // ---- prologue: stage first tile into buffer 0 ----
    STAGE_ISSUE((unsigned)bid * CPB, 0);
    __syncthreads();                      // mask zero visible before ORs
    STAGE_WRITE(0);
    __syncthreads();                      // buffer 0 ready

    int cur = 0;
    for (int k = 0; k < nt; ++k) {
        const unsigned tile = (unsigned)bid + (unsigned)k * PBLK;
        const unsigned base = tile * CPB;
        const bool hn = (k + 1 < nt);
        if (hn) STAGE_ISSUE((tile + PBLK) * CPB, cur ^ 1);

        // ================= compute tile from buf[cur] (R6 body) =============
        const unsigned img_lo = base / NCELL;
        const unsigned off    = base - img_lo * NCELL;       // 0..48

        const int p = tid & 1;
        const int s = tid >> 1;
        const unsigned rel  = ((unsigned)(s + off) * 1339u) >> 16;  // /49
        const unsigned mask = s_mask[cur][rel];
        const float2* a2 = reinterpret_cast<const float2*>(s_act4[cur]) + s * 15;

        // CE, split across the box pair (each thread: 10 classes)
        const float2* cp = a2 + 5 + p * 5;
        float2 c0 = cp[0], c1 = cp[1], c2 = cp[2], c3 = cp[3], c4 = cp[4];
        float mxh = fmaxf(fmaxf(fmaxf(c0.x, c0.y), fmaxf(c1.x, c1.y)),
                          fmaxf(fmaxf(c2.x, c2.y), fmaxf(c3.x, c3.y)));
        mxh = fmaxf(mxh, fmaxf(c4.x, c4.y));
        const unsigned mh = mask >> (p * 10);
        float selh = ((mh & 1u)   ? c0.x : 0.f) + ((mh & 2u)   ? c0.y : 0.f)
                   + ((mh & 4u)   ? c1.x : 0.f) + ((mh & 8u)   ? c1.y : 0.f)
                   + ((mh & 16u)  ? c2.x : 0.f) + ((mh & 32u)  ? c2.y : 0.f)
                   + ((mh & 64u)  ? c3.x : 0.f) + ((mh & 128u) ? c3.y : 0.f)
                   + ((mh & 256u) ? c4.x : 0.f) + ((mh & 512u) ? c4.y : 0.f);
        const float mx = fmaxf(mxh, __shfl_xor(mxh, 1));
        float ssh = __expf(c0.x - mx) + __expf(c0.y - mx)
                  + __expf(c1.x - mx) + __expf(c1.y - mx)
                  + __expf(c2.x - mx) + __expf(c2.y - mx)
                  + __expf(c3.x - mx) + __expf(c3.y - mx)
                  + __expf(c4.x - mx) + __expf(c4.y - mx);
        const float ssum = ssh + __shfl_xor(ssh, 1);
        const float sel  = selh + __shfl_xor(selh, 1);
        const float ce = (float)__popc(mask) * (mx + __logf(ssum)) - sel;

        // my box: floats [5p .. 5p+4]
        float2 A = a2[2 * p], Bv = a2[2 * p + 1], Cv = a2[2 * p + 2];
        const float cx = p ? A.y  : A.x;
        const float cy = p ? Bv.x : A.y;
        const float w  = p ? Bv.y : Bv.x;
        const float h  = p ? Cv.x : Bv.y;
        const float cf = p ? Cv.y : Cv.x;

        const float px1 = fmaf(w, -0.5f, cx), py1 = fmaf(h, -0.5f, cy);
        const float px2 = fmaf(w,  0.5f, cx), py2 = fmaf(h,  0.5f, cy);
        const float pae = w * h + EPS_IOU;

        // IoU argmax over 32 GTs (broadcast LDS reads; paired lanes share addrs)
        const float4* gtc = s_gtc[cur] + rel * NGT;
        const float*  gab = s_ga[cur]  + rel * NGT;
        float bin = -1.f, bS = 1.f;
        int bi = 0;
        #pragma unroll
        for (int j = 0; j < NGT; j += 2) {
            float4 g0 = gtc[j], g1 = gtc[j + 1];
            float2 ar = *reinterpret_cast<const float2*>(gab + j);
            {
                float iw = fmaxf(fminf(px2, g0.z) - fmaxf(px1, g0.x), 0.f);
                float ih = fmaxf(fminf(py2, g0.w) - fmaxf(py1, g0.y), 0.f);
                float in = iw * ih, S = pae + ar.x;
                if (in * bS > bin * S) { bin = in; bS = S; bi = j; }
            }
            {
                float iw = fmaxf(fminf(px2, g1.z) - fmaxf(px1, g1.x), 0.f);
                float ih = fmaxf(fminf(py2, g1.w) - fmaxf(py1, g1.y), 0.f);
                float in = iw * ih, S = pae + ar.y;
                if (in * bS > bin * S) { bin = in; bS = S; bi = j + 1; }
            }
        }

        float term;
        if (bin > 0.f) {
            float4 g = gtc[bi];
            const float iou = __fdividef(bin, bS - bin);
            const float dx = cx - (g.x + g.z) * 0.5f;
            const float dy = cy - (g.y + g.w) * 0.5f;
            const float dw = sqrtf(w) - sqrtf(g.z - g.x);
            const float dh = sqrtf(h) - sqrtf(g.w - g.y);
            term = LAMBDA_COORD * (dx * dx + dy * dy + dw * dw + dh * dh)
                 + (cf - iou) * (cf - iou) + ce;
        } else {
            term = LAMBDA_NOOBJ * cf * cf;
        }
        acc += term;
        // ====================================================================

        __syncthreads();                  // all reads of buf[cur] done
        if (hn) STAGE_WRITE(cur ^ 1);
        __syncthreads();                  // next buffer ready
        cur ^= 1;
    }

    // ---- block reduce -> 1 float per block ----
    #pragma unroll
    for (int o = 32; o > 0; o >>= 1)
        acc += __shfl_down(acc, o);
    if ((tid & 63) == 0) s_w[tid >> 6] = acc;
    __syncthreads();
    if (tid == 0)
        partials[bid] = s_w[0] + s_w[1] + s_w[2] + s_w[3];
}

__global__ __launch_bounds__(256) void yolo_reduce_kernel(
    const float* __restrict__ partials, float* __restrict__ out)
{
    float s = 0.f;
    #pragma unroll
    for (int k = 0; k < PBLK / 256; ++k)
        s += partials[threadIdx.x + k * 256];
    #pragma unroll
    for (int o = 32; o > 0; o >>= 1)
        s += __shfl_down(s, o);
    __shared__ float s_w[4];
    const int tid = threadIdx.x;
    if ((tid & 63) == 0) s_w[tid >> 6] = s;
    __syncthreads();
    if (tid == 0)
        out[0] = (s_w[0] + s_w[1] + s_w[2] + s_w[3]) * (1.0f / (float)NIMG);
}

extern "C" void kernel_launch(void* const* d_in, const int* in_sizes, int n_in,
                              void* d_out, int out_size, void* d_ws, size_t ws_size,
                              hipStream_t stream) {
    const float* outputs   = (const float*)d_in[0];
    const float* gt_boxes  = (const float*)d_in[1];
    const int*   gt_labels = (const int*)d_in[2];
    float* out      = (float*)d_out;
    float* partials = (float*)d_ws;          // PBLK floats = 4 KB

    yolo_main_kernel<<<PBLK, 256, 0, stream>>>(outputs, gt_boxes, gt_labels, partials);
    yolo_reduce_kernel<<<1, 256, 0, stream>>>(partials, out);
}

// Round 13
// 28.647 us; speedup vs baseline: 1.4466x; 1.0097x over previous
//
#include <hip/hip_runtime.h>

#define NC 20
#define NCELL 49
#define NGT 32
#define NIMG 8192
#define NTOT (NIMG * NCELL)        // 401408
#define CPB 128                    // cells per tile
#define NTILE (NTOT / CPB)         // 3136 tiles
#define PBLK 1024                  // persistent blocks = exactly 4 per CU
#define NSPAN 4                    // images spanned by 128 consecutive cells
#define LAMBDA_COORD 5.0f
#define LAMBDA_NOOBJ 0.5f
#define EPS_IOU 1e-6f

// Persistent-block, double-buffered (R12) with ONE barrier per tile:
// the LDS-atomicOr mask build is replaced by a wave-internal shuffle-OR
// (no pre-zeroing, no cross-wave ordering), so the compute->WRITE barrier
// is removable: WRITE touches only buf[cur^1], whose last readers finished
// before the previous iteration's barrier. Compute body = R6/R12 verbatim.
__global__ __launch_bounds__(256, 4) void yolo_main_kernel(
    const float* __restrict__ outputs,     // [N, 49, 30]
    const float* __restrict__ gt_boxes,    // [N, 32, 4]
    const int*   __restrict__ gt_labels,   // [N, 32]
    float* __restrict__ partials)          // [PBLK]
{
    __shared__ float4   s_act4[2][CPB * 30 / 4];   // 2 x 15360 B
    __shared__ float4   s_gtc[2][NSPAN * NGT];     // 2 x 2048 B
    __shared__ float    s_ga [2][NSPAN * NGT];     // 2 x  512 B
    __shared__ unsigned s_mask[2][NSPAN];
    __shared__ float    s_w[4];

    const int tid = threadIdx.x;
    const int bid = blockIdx.x;
    const int nt  = 3 + (bid < (NTILE - 3 * PBLK) ? 1 : 0);   // first 64 get 4

    float acc = 0.f;

    // prefetch registers (live across compute)
    float4 r0, r1, r2, r3, gtr;
    unsigned labbit = 0u;
    unsigned g_img = NIMG;   // staging thread's image (predication)

#define STAGE_ISSUE(base_) do {                                               \
    const float4* asrc_ = reinterpret_cast<const float4*>(outputs)            \
                        + (size_t)(base_) * 30 / 4;                           \
    r0 = asrc_[tid];                                                          \
    r1 = asrc_[tid + 256];                                                    \
    r2 = asrc_[tid + 512];                                                    \
    if (tid < 192) r3 = asrc_[tid + 768];                                     \
    const unsigned il_ = (base_) / NCELL;                                     \
    if (tid < 128) {                                                          \
        const unsigned g_ = (unsigned)tid >> 5;                               \
        g_img = il_ + g_;                                                     \
        if (g_img < NIMG)                                                     \
            gtr = reinterpret_cast<const float4*>(gt_boxes)[g_img * NGT + (tid & 31)]; \
    } else {                                                                  \
        const int t_ = tid - 128;                                             \
        const unsigned g_ = (unsigned)t_ >> 5;                                \
        g_img = il_ + g_;                                                     \
        labbit = (g_img < NIMG) ? (1u << gt_labels[g_img * NGT + (t_ & 31)])  \
                                : 0u;                                         \
    }                                                                         \
} while (0)

#define STAGE_WRITE(nb_) do {                                                 \
    s_act4[nb_][tid]       = r0;                                              \
    s_act4[nb_][tid + 256] = r1;                                              \
    s_act4[nb_][tid + 512] = r2;                                              \
    if (tid < 192) s_act4[nb_][tid + 768] = r3;                               \
    if (tid < 128) {                                                          \
        if (g_img < NIMG) {                                                   \
            s_gtc[nb_][tid] = make_float4(fmaf(gtr.z, -0.5f, gtr.x),          \
                                          fmaf(gtr.w, -0.5f, gtr.y),          \
                                          fmaf(gtr.z,  0.5f, gtr.x),          \
                                          fmaf(gtr.w,  0.5f, gtr.y));         \
            s_ga[nb_][tid] = gtr.z * gtr.w;                                   \
        }                                                                     \
    } else {                                                                  \
        unsigned m_ = labbit;                                                 \
        m_ |= __shfl_xor(m_, 1, 32);                                          \
        m_ |= __shfl_xor(m_, 2, 32);                                          \
        m_ |= __shfl_xor(m_, 4, 32);                                          \
        m_ |= __shfl_xor(m_, 8, 32);                                          \
        m_ |= __shfl_xor(m_, 16, 32);                                         \
        const int t_ = tid - 128;                                             \
        if ((t_ & 31) == 0) s_mask[nb_][t_ >> 5] = m_;                        \
    }                                                                         \
} while (0)

    // ---- prologue: stage first tile into buffer 0, single barrier ----
    STAGE_ISSUE((unsigned)bid * CPB);
    STAGE_WRITE(0);
    __syncthreads();                      // buffer 0 ready

    int cur = 0;
    for (int k = 0; k < nt; ++k) {
        const unsigned tile = (unsigned)bid + (unsigned)k * PBLK;
        const unsigned base = tile * CPB;
        const bool hn = (k + 1 < nt);
        if (hn) STAGE_ISSUE((tile + PBLK) * CPB);

        // ================= compute tile from buf[cur] (R6 body) =============
        const unsigned img_lo = base / NCELL;
        const unsigned off    = base - img_lo * NCELL;       // 0..48

        const int p = tid & 1;
        const int s = tid >> 1;
        const unsigned rel  = ((unsigned)(s + off) * 1339u) >> 16;  // /49
        const unsigned mask = s_mask[cur][rel];
        const float2* a2 = reinterpret_cast<const float2*>(s_act4[cur]) + s * 15;

        // CE, split across the box pair (each thread: 10 classes)
        const float2* cp = a2 + 5 + p * 5;
        float2 c0 = cp[0], c1 = cp[1], c2 = cp[2], c3 = cp[3], c4 = cp[4];
        float mxh = fmaxf(fmaxf(fmaxf(c0.x, c0.y), fmaxf(c1.x, c1.y)),
                          fmaxf(fmaxf(c2.x, c2.y), fmaxf(c3.x, c3.y)));
        mxh = fmaxf(mxh, fmaxf(c4.x, c4.y));
        const unsigned mh = mask >> (p * 10);
        float selh = ((mh & 1u)   ? c0.x : 0.f) + ((mh & 2u)   ? c0.y : 0.f)
                   + ((mh & 4u)   ? c1.x : 0.f) + ((mh & 8u)   ? c1.y : 0.f)
                   + ((mh & 16u)  ? c2.x : 0.f) + ((mh & 32u)  ? c2.y : 0.f)
                   + ((mh & 64u)  ? c3.x : 0.f) + ((mh & 128u) ? c3.y : 0.f)
                   + ((mh & 256u) ? c4.x : 0.f) + ((mh & 512u) ? c4.y : 0.f);
        const float mx = fmaxf(mxh, __shfl_xor(mxh, 1));
        float ssh = __expf(c0.x - mx) + __expf(c0.y - mx)
                  + __expf(c1.x - mx) + __expf(c1.y - mx)
                  + __expf(c2.x - mx) + __expf(c2.y - mx)
                  + __expf(c3.x - mx) + __expf(c3.y - mx)
                  + __expf(c4.x - mx) + __expf(c4.y - mx);
        const float ssum = ssh + __shfl_xor(ssh, 1);
        const float sel  = selh + __shfl_xor(selh, 1);
        const float ce = (float)__popc(mask) * (mx + __logf(ssum)) - sel;

        // my box: floats [5p .. 5p+4]
        float2 A = a2[2 * p], Bv = a2[2 * p + 1], Cv = a2[2 * p + 2];
        const float cx = p ? A.y  : A.x;
        const float cy = p ? Bv.x : A.y;
        const float w  = p ? Bv.y : Bv.x;
        const float h  = p ? Cv.x : Bv.y;
        const float cf = p ? Cv.y : Cv.x;

        const float px1 = fmaf(w, -0.5f, cx), py1 = fmaf(h, -0.5f, cy);
        const float px2 = fmaf(w,  0.5f, cx), py2 = fmaf(h,  0.5f, cy);
        const float pae = w * h + EPS_IOU;

        // IoU argmax over 32 GTs (broadcast LDS reads)
        const float4* gtc = s_gtc[cur] + rel * NGT;
        const float*  gab = s_ga[cur]  + rel * NGT;
        float bin = -1.f, bS = 1.f;
        int bi = 0;
        #pragma unroll
        for (int j = 0; j < NGT; j += 2) {
            float4 g0 = gtc[j], g1 = gtc[j + 1];
            float2 ar = *reinterpret_cast<const float2*>(gab + j);
            {
                float iw = fmaxf(fminf(px2, g0.z) - fmaxf(px1, g0.x), 0.f);
                float ih = fmaxf(fminf(py2, g0.w) - fmaxf(py1, g0.y), 0.f);
                float in = iw * ih, S = pae + ar.x;
                if (in * bS > bin * S) { bin = in; bS = S; bi = j; }
            }
            {
                float iw = fmaxf(fminf(px2, g1.z) - fmaxf(px1, g1.x), 0.f);
                float ih = fmaxf(fminf(py2, g1.w) - fmaxf(py1, g1.y), 0.f);
                float in = iw * ih, S = pae + ar.y;
                if (in * bS > bin * S) { bin = in; bS = S; bi = j + 1; }
            }
        }

        float term;
        if (bin > 0.f) {
            float4 g = gtc[bi];
            const float iou = __fdividef(bin, bS - bin);
            const float dx = cx - (g.x + g.z) * 0.5f;
            const float dy = cy - (g.y + g.w) * 0.5f;
            const float dw = sqrtf(w) - sqrtf(g.z - g.x);
            const float dh = sqrtf(h) - sqrtf(g.w - g.y);
            term = LAMBDA_COORD * (dx * dx + dy * dy + dw * dw + dh * dh)
                 + (cf - iou) * (cf - iou) + ce;
        } else {
            term = LAMBDA_NOOBJ * cf * cf;
        }
        acc += term;
        // ====================================================================

        if (hn) STAGE_WRITE(cur ^ 1);     // writes buf[cur^1] only: no conflict
        __syncthreads();                  // next buffer ready; cur reads done
        cur ^= 1;
    }

    // ---- block reduce -> 1 float per block ----
    #pragma unroll
    for (int o = 32; o > 0; o >>= 1)
        acc += __shfl_down(acc, o);
    if ((tid & 63) == 0) s_w[tid >> 6] = acc;
    __syncthreads();
    if (tid == 0)
        partials[bid] = s_w[0] + s_w[1] + s_w[2] + s_w[3];
}

__global__ __launch_bounds__(256) void yolo_reduce_kernel(
    const float* __restrict__ partials, float* __restrict__ out)
{
    float s = 0.f;
    #pragma unroll
    for (int k = 0; k < PBLK / 256; ++k)
        s += partials[threadIdx.x + k * 256];
    #pragma unroll
    for (int o = 32; o > 0; o >>= 1)
        s += __shfl_down(s, o);
    __shared__ float s_w[4];
    const int tid = threadIdx.x;
    if ((tid & 63) == 0) s_w[tid >> 6] = s;
    __syncthreads();
    if (tid == 0)
        out[0] = (s_w[0] + s_w[1] + s_w[2] + s_w[3]) * (1.0f / (float)NIMG);
}

extern "C" void kernel_launch(void* const* d_in, const int* in_sizes, int n_in,
                              void* d_out, int out_size, void* d_ws, size_t ws_size,
                              hipStream_t stream) {
    const float* outputs   = (const float*)d_in[0];
    const float* gt_boxes  = (const float*)d_in[1];
    const int*   gt_labels = (const int*)d_in[2];
    float* out      = (float*)d_out;
    float* partials = (float*)d_ws;          // PBLK floats = 4 KB

    yolo_main_kernel<<<PBLK, 256, 0, stream>>>(outputs, gt_boxes, gt_labels, partials);
    yolo_reduce_kernel<<<1, 256, 0, stream>>>(partials, out);
}